// Round 4
// baseline (326.903 us; speedup 1.0000x reference)
//
#include <hip/hip_runtime.h>
#include <hip/hip_bf16.h>
#include <stdint.h>

// ---------------------------------------------------------------------------
// TensorizedGRU: m[b,l] = sum_{j,k} s[b,j] x[b,k] W[l,j,k]  (l in [0,256): W1||W2)
// R13 = R12 (133.3us, MfmaUtil 47.5) with the MFMA shape switched to
// 32x32x16 (same FLOPs, -17% matrix-pipe cyc [m119 2495 vs m06 2075 TF],
// and 16 instead of 32 MFMA instr per chunk -> shorter per-wave issue path,
// which R11/R12 showed sets the round time ~1:1).
//  - Wave owns ONE 32-col n-slice (n32 = nt*4+wave); per chunk (j,q): 4 B-frags
//    (ksub 0..3, K=16 each) chained into m0 (K=64), then racc += sv * m0.
//  - A/B frag layout: [dim = lane%32][k = 8*(lane/32) + reg] (generalization
//    of the verified 16x16x32 pattern); C/D: col=lane&31,
//    row=(reg&3)+8*(reg>>2)+4*(lane>>5) (HW-verified, learn_hip m74/m101).
//  - prep_wx re-orders Wt fragments for the 32-wide B mapping (same 1KB frags,
//    same total layout/sizes). Epilogue: grid 1024 (4 rows/blk) + unroll 8.
// ws layout:
//   Wt   bf16 [256][65536]  @ 0          (33,554,432 B)  fragment-ordered
//   x_bf bf16 [4096][256]   @ 32MiB+2MiB ( 2,097,152 B)
//   Mpart f32 [8][4096][256]@ +2MiB      (33,554,432 B)
// ---------------------------------------------------------------------------

typedef short bf8 __attribute__((ext_vector_type(8)));    // 8 bf16 = 4 VGPRs
typedef float f32x4 __attribute__((ext_vector_type(4)));
typedef float f32x16 __attribute__((ext_vector_type(16)));

static constexpr size_t WT_OFF  = 0;
static constexpr size_t XBF_OFF = 33554432 + 2097152;
static constexpr size_t MP_OFF  = XBF_OFF + 2097152;

// round-to-nearest-even f32 -> bf16 (finite inputs only)
__device__ __forceinline__ unsigned f2bf(float f) {
    unsigned u = __builtin_bit_cast(unsigned, f);
    return (u + 0x7fffu + ((u >> 16) & 1u)) >> 16;
}
__device__ __forceinline__ unsigned pack2bf(float a, float b) {
    return f2bf(a) | (f2bf(b) << 16);
}

// ---------------- prep: fragment-ordered Wt (wave-per-frag) + x cast --------
// Fragment f = ((n32*1024 + kchunk)*4 + ksub), f in [0, 32768), 1KB each.
// Frag content (32x32x16 B-operand): lane l holds
//   W[n32*32 + (l&31)][kchunk*64 + ksub*16 + (l>>5)*8 .. +8)  as 8 bf16.
// Blocks 0..8191: 4 waves/block, wave w makes frag f = bx*4 + w.
// Blocks 8192..9215: x = in0||in1 -> bf16 (row-major [4096][256]).
__global__ void prep_wx(const float* __restrict__ W1, const float* __restrict__ W2,
                        const float* __restrict__ in0, const float* __restrict__ in1,
                        uint4* __restrict__ Wt, unsigned* __restrict__ x_bf) {
    int bx = blockIdx.x;
    if (bx < 8192) {
        const int tid  = threadIdx.x;
        const int lane = tid & 63, wave = tid >> 6;
        const unsigned f = bx * 4 + wave;
        const unsigned n32 = f >> 12;
        const unsigned kchunk = (f >> 2) & 1023u;
        const unsigned ksub = f & 3u;
        const unsigned n = n32 * 32 + (lane & 31);
        const unsigned K = kchunk * 64 + ksub * 16 + (lane >> 5) * 8;
        const float* src = (n < 128 ? W1 + ((size_t)n << 16)
                                    : W2 + ((size_t)(n - 128) << 16)) + K;
        float4 a = ((const float4*)src)[0];
        float4 b = ((const float4*)src)[1];
        uint4 o;
        o.x = pack2bf(a.x, a.y); o.y = pack2bf(a.z, a.w);
        o.z = pack2bf(b.x, b.y); o.w = pack2bf(b.z, b.w);
        Wt[(size_t)f * 64 + lane] = o;        // contiguous 1KB per wave
    } else {
        unsigned v = (bx - 8192) * 256 + threadIdx.x; // 262,144 units of 4 elems
        unsigned b = v >> 6;
        unsigned j4 = (v & 63u) * 4u;
        const float* src = (j4 < 128) ? (in0 + (size_t)b * 128 + j4)
                                      : (in1 + (size_t)b * 128 + (j4 - 128));
        float4 a = *(const float4*)src;
        uint2 o;
        o.x = pack2bf(a.x, a.y);
        o.y = pack2bf(a.z, a.w);
        ((uint2*)x_bf)[v] = o;
    }
}

// ---------------- main GEMM: 128x128 tile, split-K=8, barrier-free ----------
// grid 512: ks = bx&7 (XCD-pinned), nt = (bx>>3)&1, mt = bx>>4 (0..31).
// block 256 = 4 waves; wave w owns n32 = nt*4+w (32 n-cols), all 128 m-rows.
__launch_bounds__(256, 2)
__global__ void gemm_p(const unsigned char* __restrict__ Wt,
                       const float* __restrict__ st0, const float* __restrict__ st1,
                       const __hip_bfloat16* __restrict__ x_bf,
                       float* __restrict__ Mpart) {
    const int bx = blockIdx.x;
    const int ks = bx & 7;                  // split-K slice, pinned per XCD
    const int nt = (bx >> 3) & 1;
    const int mt = bx >> 4;
    const int b0 = mt << 7, n0 = nt << 7;
    const int tid  = threadIdx.x;
    const int lane = tid & 63, wave = tid >> 6;
    const int l31 = lane & 31, hi = lane >> 5;

    // s tile: [32 j][132 r] f32 (pad to 132 -> broadcast-clean)
    __shared__ __align__(16) float Sl[32 * 132];
    for (int idx = tid; idx < 4096; idx += 256) {
        int r = idx >> 5, j = idx & 31;
        int jg = ks * 32 + j;
        float v = (jg < 128) ? st0[(size_t)(b0 + r) * 128 + jg]
                             : st1[(size_t)(b0 + r) * 128 + (jg - 128)];
        Sl[j * 132 + r] = v;
    }
    __syncthreads();                        // the ONLY barrier

    // Wave-uniform Wt slice base in SGPR: n32-slice is 4 MiB (1<<22).
    const int n32 = __builtin_amdgcn_readfirstlane(nt * 4 + wave);
    const unsigned char* wb = Wt + ((size_t)n32 << 22);

    f32x16 racc[4];
    #pragma unroll
    for (int mf = 0; mf < 4; ++mf)
        #pragma unroll
        for (int e = 0; e < 16; ++e) racc[mf][e] = 0.f;
    f32x16 z16;
    #pragma unroll
    for (int e = 0; e < 16; ++e) z16[e] = 0.f;

    bf8 a[4][4];                            // [mf 32-row block][ksub], per q
    bf8 buf[2][4];                          // [ping][ksub] B-frags

    // Running within-slice byte offset:
    // addr(j,q) = lane*16 + ks*524288 + j*16384 + q*4096   (ksub*1024 in imm)
    unsigned vo = (unsigned)lane * 16u + (unsigned)ks * 524288u;

    for (int q = 0; q < 4; ++q) {
        // A-frags for this x-quadrant (x_bf row-major, L2-resident)
        #pragma unroll
        for (int mf = 0; mf < 4; ++mf) {
            const __hip_bfloat16* xp =
                x_bf + (size_t)((b0 + mf * 32 + l31) * 256 + q * 64 + hi * 8);
            #pragma unroll
            for (int ksub = 0; ksub < 4; ++ksub)
                a[mf][ksub] = *(const bf8*)(xp + ksub * 16);
        }
        // peel j=0 B-frags (one exposed latency per 32 chunks)
        #pragma unroll
        for (int ksub = 0; ksub < 4; ++ksub)
            buf[0][ksub] = *(const bf8*)(wb + vo + ksub * 1024);
        vo += 16384;                         // -> prefetch target j=1

        const float* svp = Sl + hi * 4;      // s broadcast ptr, +132/chunk

        for (int jb = 0; jb < 16; ++jb) {
            #pragma unroll
            for (int jj = 0; jj < 2; ++jj) {
                const int pp = jj;           // j = jb*2+jj -> pp = j&1
                // prefetch next chunk's B-frags (last iter overshoots into
                // valid ws; values discarded at q boundary)
                #pragma unroll
                for (int ksub = 0; ksub < 4; ++ksub)
                    buf[pp ^ 1][ksub] = *(const bf8*)(wb + vo + ksub * 1024);
                vo += 16384;
                // 16 MFMA (4 chains of K=64) + f32 scale-accumulate
                #pragma unroll
                for (int mf = 0; mf < 4; ++mf) {
                    f32x16 m0 = __builtin_amdgcn_mfma_f32_32x32x16_bf16(a[mf][0], buf[pp][0], z16, 0, 0, 0);
                    m0 = __builtin_amdgcn_mfma_f32_32x32x16_bf16(a[mf][1], buf[pp][1], m0, 0, 0, 0);
                    m0 = __builtin_amdgcn_mfma_f32_32x32x16_bf16(a[mf][2], buf[pp][2], m0, 0, 0, 0);
                    m0 = __builtin_amdgcn_mfma_f32_32x32x16_bf16(a[mf][3], buf[pp][3], m0, 0, 0, 0);
                    // sv rows for C-layout: row = mf*32 + g*8 + hi*4 + t
                    #pragma unroll
                    for (int g = 0; g < 4; ++g) {
                        f32x4 sg = *(const f32x4*)(svp + mf * 32 + g * 8);
                        #pragma unroll
                        for (int t = 0; t < 4; ++t)
                            racc[mf][g * 4 + t] += sg[t] * m0[g * 4 + t];
                    }
                }
                svp += 132;
            }
        }
        vo += 4096 - 33 * 16384;             // rewind to (q+1, j=0)
    }

    // split-K partial stores (32x32 C layout: col=l31, row=(r&3)+8*(r>>2)+4*hi)
    float* mp = Mpart + ((size_t)ks << 20);
    const int n = n0 + (n32 & 3) * 32 + l31;
    #pragma unroll
    for (int mf = 0; mf < 4; ++mf)
        #pragma unroll
        for (int r = 0; r < 16; ++r) {
            int row = b0 + mf * 32 + (r & 3) + 8 * (r >> 2) + 4 * hi;
            mp[(size_t)row * 256 + n] = racc[mf][r];
        }
}

// ---------------- epilogue: reduce split-K, s@W3, activations, blend --------
// grid 1024 (4 rows/block) + unroll 8 on the W3 loop: more blocks/CU and
// more outstanding W3 loads to hide L2 latency.
__global__ void epilogue(const float* __restrict__ st0, const float* __restrict__ st1,
                         const float* __restrict__ b1, const float* __restrict__ b2,
                         const float* __restrict__ W3, const float* __restrict__ Mpart,
                         float* __restrict__ out) {
    const int tid = threadIdx.x;
    const int h = tid & 127, rg = tid >> 7;          // rg in {0,1}
    const int bbase = blockIdx.x * 4;                // 4 rows per block
    __shared__ float srow[4][256];
    #pragma unroll
    for (int i = 0; i < 4; ++i) {
        int idx = i * 256 + tid;
        int r = idx >> 8, j = idx & 255;
        float v = (j < 128) ? st0[(size_t)(bbase + r) * 128 + j]
                            : st1[(size_t)(bbase + r) * 128 + (j - 128)];
        srow[r][j] = v;
    }
    __syncthreads();
    float acc0 = 0.f, acc1 = 0.f;
    #pragma unroll 8
    for (int j = 0; j < 256; ++j) {
        float w = W3[j * 128 + h];
        acc0 += srow[rg][j] * w;
        acc1 += srow[rg + 2][j] * w;
    }
    float accs[2] = {acc0, acc1};
    float bb1 = b1[h], bb2 = b2[h];
    #pragma unroll
    for (int i = 0; i < 2; ++i) {
        int b = bbase + rg + i * 2;
        float m1 = 0.f, m2 = 0.f;
        #pragma unroll
        for (int k = 0; k < 8; ++k) {
            m1 += Mpart[((size_t)k << 20) + (size_t)b * 256 + h];
            m2 += Mpart[((size_t)k << 20) + (size_t)b * 256 + 128 + h];
        }
        float u = 1.0f / (1.0f + expf(-(m2 + bb2)));
        float t = tanhf(m1 + bb1);
        out[(size_t)b * 128 + h] = u * t + (1.0f - u) * accs[i];
    }
}

extern "C" void kernel_launch(void* const* d_in, const int* in_sizes, int n_in,
                              void* d_out, int out_size, void* d_ws, size_t ws_size,
                              hipStream_t stream) {
    const float* in0 = (const float*)d_in[0];
    const float* in1 = (const float*)d_in[1];
    const float* st0 = (const float*)d_in[2];
    const float* st1 = (const float*)d_in[3];
    const float* W1  = (const float*)d_in[4];
    const float* b1  = (const float*)d_in[5];
    const float* W2  = (const float*)d_in[6];
    const float* b2  = (const float*)d_in[7];
    const float* W3  = (const float*)d_in[8];
    float* out = (float*)d_out;
    char* ws = (char*)d_ws;

    unsigned char* Wt   = (unsigned char*)(ws + WT_OFF);
    unsigned*      x_bf = (unsigned*)(ws + XBF_OFF);
    float*         Mp   = (float*)(ws + MP_OFF);

    prep_wx<<<9216, 256, 0, stream>>>(W1, W2, in0, in1, (uint4*)Wt, x_bf);
    gemm_p<<<512, 256, 0, stream>>>(Wt, st0, st1, (const __hip_bfloat16*)x_bf, Mp);
    epilogue<<<1024, 256, 0, stream>>>(st0, st1, b1, b2, W3, Mp, out);
}